// Round 2
// baseline (2927.822 us; speedup 1.0000x reference)
//
#include <hip/hip_runtime.h>
#include <cstdint>

#define NF 65536
#define PL 8
#define NL 4096
#define PPL 128

__device__ __forceinline__ float sigm(float v) { return 1.0f / (1.0f + __expf(-v)); }
__device__ __forceinline__ float tanhfast(float v) {
    float e = __expf(2.0f * v);
    return 1.0f - 2.0f / (e + 1.0f);
}
__device__ __forceinline__ float seluf(float x) {
    return x > 0.0f ? 1.0507009873554805f * x : 1.7580993408473766f * (__expf(x) - 1.0f);
}
__device__ __forceinline__ unsigned short f2bf(float x) {
    unsigned u = __float_as_uint(x);
    u += 0x7fffu + ((u >> 16) & 1u);
    return (unsigned short)(u >> 16);
}
__device__ __forceinline__ float bflo(unsigned u) { return __uint_as_float(u << 16); }
__device__ __forceinline__ float bfhi(unsigned u) { return __uint_as_float(u & 0xffff0000u); }

// Cubic B-spline basis, 8 bases, knots t_j = (j-3)*0.4 - 1 (matches jnp _knots)
__device__ __forceinline__ void bspline8(float xx, float* B) {
    float kn[12];
#pragma unroll
    for (int j = 0; j < 12; ++j) kn[j] = (float)(j - 3) * 0.4f - 1.0f;
    float b0[11];
#pragma unroll
    for (int j = 0; j < 11; ++j) b0[j] = (xx >= kn[j] && xx < kn[j + 1]) ? 1.0f : 0.0f;
    float b1[10];
#pragma unroll
    for (int j = 0; j < 10; ++j)
        b1[j] = (xx - kn[j]) * (1.0f / (kn[j + 1] - kn[j])) * b0[j] +
                (kn[j + 2] - xx) * (1.0f / (kn[j + 2] - kn[j + 1])) * b0[j + 1];
    float b2[9];
#pragma unroll
    for (int j = 0; j < 9; ++j)
        b2[j] = (xx - kn[j]) * (1.0f / (kn[j + 2] - kn[j])) * b1[j] +
                (kn[j + 3] - xx) * (1.0f / (kn[j + 3] - kn[j + 1])) * b1[j + 1];
#pragma unroll
    for (int j = 0; j < 8; ++j)
        B[j] = (xx - kn[j]) * (1.0f / (kn[j + 3] - kn[j])) * b2[j] +
               (kn[j + 4] - xx) * (1.0f / (kn[j + 4] - kn[j + 1])) * b2[j + 1];
}

// ---------------- S1: per-link load ----------------
__global__ __launch_bounds__(256) void k_load(const int* __restrict__ p2l,
                                              const float* __restrict__ ft,
                                              const float* __restrict__ cap,
                                              float* __restrict__ load) {
    int gid = blockIdx.x * 256 + threadIdx.x;
    int link = gid >> 6;
    int lane = threadIdx.x & 63;
    const int2* b2 = (const int2*)(p2l + (size_t)link * PPL * 2);
    int2 v0 = b2[lane];
    int2 v1 = b2[lane + 64];
    float s = ft[v0.x] + ft[v1.x];
#pragma unroll
    for (int off = 32; off; off >>= 1) s += __shfl_xor(s, off);
    if (lane == 0) load[link] = s / (cap[link] * 1e9f);
}

// ---------------- S2: flow encoder -> path_state ----------------
__global__ __launch_bounds__(256) void k_flow_enc(
    const float* __restrict__ tr, const float* __restrict__ pk,
    const float* __restrict__ ppb, const float* __restrict__ bpb,
    const float* __restrict__ psz, const float* __restrict__ p90,
    const float* __restrict__ rate, const float* __restrict__ ipgm,
    const float* __restrict__ ibg, const float* __restrict__ ipgv,
    const float* __restrict__ ftype, const int* __restrict__ flen,
    const float* __restrict__ w1, const float* __restrict__ b1,
    const float* __restrict__ w2, const float* __restrict__ b2,
    float* __restrict__ ps) {
    __shared__ float sw1[13 * 16], sb1[16], sw2[256], sb2[16];
    int tid = threadIdx.x;
    if (tid < 208) sw1[tid] = w1[tid];
    sw2[tid] = w2[tid];
    if (tid < 16) { sb1[tid] = b1[tid]; sb2[tid] = b2[tid]; }
    __syncthreads();
    int f = blockIdx.x * 256 + tid;
    float feat[13];
    feat[0] = (tr[f] - 0.5f) * 2.0f;
    feat[1] = (pk[f] - 0.5f) * 2.0f;
    feat[2] = (ibg[f] - 0.5f) * 2.0f;
    feat[3] = (rate[f] - 0.5f) * 2.0f;
    feat[4] = (p90[f] - 0.5f) * 2.0f;
    feat[5] = (psz[f] - 0.5f) * 2.0f;
    feat[6] = (bpb[f] - 0.5f) * 2.0f;
    feat[7] = (ipgm[f] - 0.5f) * 2.0f;
    feat[8] = (ipgv[f] - 0.5f) * 2.0f;
    feat[9] = (ppb[f] - 0.5f) * 2.0f;
    feat[10] = (float)flen[f];
    float2 ft2 = ((const float2*)ftype)[f];
    feat[11] = ft2.x;
    feat[12] = ft2.y;
    float t1[16];
#pragma unroll
    for (int u = 0; u < 16; ++u) {
        float a = sb1[u];
#pragma unroll
        for (int i = 0; i < 13; ++i) a += feat[i] * sw1[i * 16 + u];
        t1[u] = seluf(a);
    }
    float out[16];
#pragma unroll
    for (int u = 0; u < 16; ++u) {
        float a = sb2[u];
#pragma unroll
        for (int i = 0; i < 16; ++i) a += t1[i] * sw2[i * 16 + u];
        out[u] = seluf(a);
    }
    float4* o4 = (float4*)(ps + (size_t)f * 16);
    const float4* s4 = (const float4*)out;
#pragma unroll
    for (int q = 0; q < 4; ++q) o4[q] = s4[q];
}

// ---------------- S3: link encoder -> link_state (+ xk fold) ----------------
__global__ __launch_bounds__(256) void k_link_enc(
    const float* __restrict__ cap, const float* __restrict__ load,
    const float* __restrict__ mll,
    const float* __restrict__ w1, const float* __restrict__ b1,
    const float* __restrict__ w2, const float* __restrict__ b2,
    float* __restrict__ ls, float* __restrict__ xk,
    const float* __restrict__ pgk, const float* __restrict__ pgb) {
    int l = blockIdx.x * 256 + threadIdx.x;
    if (l >= NL) return;
    float f0 = (cap[l] - 5.0f) * 0.25f;
    float f1 = load[l];
    float f2 = f1 / mll[0];
    float f3 = 8.0f / 32768.0f;
    float t1[16];
#pragma unroll
    for (int u = 0; u < 16; ++u) {
        float a = b1[u] + f0 * w1[u] + f1 * w1[16 + u] + f2 * w1[32 + u] + f3 * w1[48 + u];
        t1[u] = seluf(a);
    }
    float out[16];
#pragma unroll
    for (int u = 0; u < 16; ++u) {
        float a = b2[u];
#pragma unroll
        for (int i = 0; i < 16; ++i) a += t1[i] * w2[i * 16 + u];
        out[u] = seluf(a);
    }
    float4* o4 = (float4*)(ls + (size_t)l * 16);
    const float4* s4 = (const float4*)out;
#pragma unroll
    for (int q = 0; q < 4; ++q) o4[q] = s4[q];
    // xk fold: xk[l][u] = pgb[u] + ls[l] @ pgk[:, u]
    for (int u = 0; u < 48; ++u) {
        float a = pgb[u];
#pragma unroll
        for (int i = 0; i < 16; ++i) a += out[i] * pgk[i * 48 + u];
        xk[(size_t)l * 48 + u] = a;
    }
}

// ---------------- K1: path GRU, 4 threads per flow ----------------
// MODE 0: f32 seq [f][9][16] rows 0..8 (fallback);
// MODE 1: bf16 seq [t][NF][16] rows 0..7 (attention layout);
// MODE 2: f32 seqF [f][8][16] rows 1..8 (KAN input, last iter)
template <int MODE>
__global__ __launch_bounds__(256, 4) void k_path4(
    const float* __restrict__ xk, const int* __restrict__ ltp,
    float* __restrict__ ps, unsigned short* __restrict__ seqb,
    float* __restrict__ seqf,
    const float* __restrict__ grk, const float* __restrict__ gb) {
    __shared__ float srk[768], sbg[48];
    int tid = threadIdx.x;
    for (int i = tid; i < 768; i += 256) srk[i] = grk[i];
    if (tid < 48) sbg[tid] = gb[48 + tid];
    __syncthreads();
    int gid = blockIdx.x * 256 + tid;
    int f = gid >> 2, sub = gid & 3;
    float h[4];
    *(float4*)h = *(const float4*)(ps + (size_t)f * 16 + sub * 4);
    if (MODE == 0) {
        *(float4*)(seqf + (size_t)f * 9 * 16 + sub * 4) = *(float4*)h;
    } else if (MODE == 1) {
        ushort4 u4;
        u4.x = f2bf(h[0]); u4.y = f2bf(h[1]); u4.z = f2bf(h[2]); u4.w = f2bf(h[3]);
        *(ushort4*)(seqb + (size_t)f * 16 + sub * 4) = u4;  // row 0
    }
    for (int t = 0; t < 8; ++t) {
        int lk = ltp[(size_t)f * 8 + t];
        const float* xb = xk + (size_t)lk * 48 + sub * 4;
        float az[4], ar[4], ac[4], gz[4], gr[4], gc[4];
        *(float4*)az = *(const float4*)xb;
        *(float4*)ar = *(const float4*)(xb + 16);
        *(float4*)ac = *(const float4*)(xb + 32);
        *(float4*)gz = *(const float4*)(sbg + sub * 4);
        *(float4*)gr = *(const float4*)(sbg + 16 + sub * 4);
        *(float4*)gc = *(const float4*)(sbg + 32 + sub * 4);
#pragma unroll
        for (int i = 0; i < 16; ++i) {
            float hi = __shfl(h[i & 3], i >> 2, 4);
            const float* w = srk + i * 48 + sub * 4;
            float4 wz = *(const float4*)w;
            float4 wr = *(const float4*)(w + 16);
            float4 wc = *(const float4*)(w + 32);
            gz[0] += hi * wz.x; gz[1] += hi * wz.y; gz[2] += hi * wz.z; gz[3] += hi * wz.w;
            gr[0] += hi * wr.x; gr[1] += hi * wr.y; gr[2] += hi * wr.z; gr[3] += hi * wr.w;
            gc[0] += hi * wc.x; gc[1] += hi * wc.y; gc[2] += hi * wc.z; gc[3] += hi * wc.w;
        }
#pragma unroll
        for (int j = 0; j < 4; ++j) {
            float z = sigm(az[j] + gz[j]);
            float r = sigm(ar[j] + gr[j]);
            float c = tanhfast(ac[j] + r * gc[j]);
            h[j] = z * h[j] + (1.0f - z) * c;
        }
        if (MODE == 0) {
            *(float4*)(seqf + ((size_t)f * 9 + t + 1) * 16 + sub * 4) = *(float4*)h;
        } else if (MODE == 1) {
            if (t < 7) {  // row 8 is never gathered (p_pos < 8)
                ushort4 u4;
                u4.x = f2bf(h[0]); u4.y = f2bf(h[1]); u4.z = f2bf(h[2]); u4.w = f2bf(h[3]);
                *(ushort4*)(seqb + ((size_t)(t + 1) * NF + f) * 16 + sub * 4) = u4;
            }
        } else {
            *(float4*)(seqf + ((size_t)f * 8 + t) * 16 + sub * 4) = *(float4*)h;
        }
    }
    if (MODE != 2) *(float4*)(ps + (size_t)f * 16 + sub * 4) = *(float4*)h;
}

// ---------------- K2: attention message + link GRU (+ xk fold) ----------------
template <bool BF16>
__global__ __launch_bounds__(128) void k_link_upd(
    const void* __restrict__ seqv, const int* __restrict__ p2l,
    float* __restrict__ ls,
    const float* __restrict__ aw, const float* __restrict__ ab,
    const float* __restrict__ gk, const float* __restrict__ grk,
    const float* __restrict__ gb,
    float* __restrict__ xk, const float* __restrict__ pgk,
    const float* __restrict__ pgb) {
    __shared__ float sW[256], sB[16], red[128][17], sh[16], sh2[16];
    int tid = threadIdx.x;
    int link = blockIdx.x;
    sW[tid] = aw[tid];
    sW[tid + 128] = aw[tid + 128];
    if (tid < 16) sB[tid] = ab[tid];
    __syncthreads();
    int2 pp = ((const int2*)p2l)[(size_t)link * PPL + tid];
    float pg[16];
    if (BF16) {
        const unsigned short* sp =
            (const unsigned short*)seqv + ((size_t)pp.y * NF + pp.x) * 16;
        uint4 q0 = *(const uint4*)sp;
        uint4 q1 = *(const uint4*)(sp + 8);
        pg[0] = bflo(q0.x); pg[1] = bfhi(q0.x); pg[2] = bflo(q0.y); pg[3] = bfhi(q0.y);
        pg[4] = bflo(q0.z); pg[5] = bfhi(q0.z); pg[6] = bflo(q0.w); pg[7] = bfhi(q0.w);
        pg[8] = bflo(q1.x); pg[9] = bfhi(q1.x); pg[10] = bflo(q1.y); pg[11] = bfhi(q1.y);
        pg[12] = bflo(q1.z); pg[13] = bfhi(q1.z); pg[14] = bflo(q1.w); pg[15] = bfhi(q1.w);
    } else {
        const float4* pv =
            (const float4*)((const float*)seqv + ((size_t)pp.x * 9 + pp.y) * 16);
        float4* pr = (float4*)pg;
        pr[0] = pv[0]; pr[1] = pv[1]; pr[2] = pv[2]; pr[3] = pv[3];
    }
    float at[16];
#pragma unroll
    for (int u = 0; u < 16; ++u) {
        float a = sB[u];
#pragma unroll
        for (int i = 0; i < 16; ++i) a += pg[i] * sW[i * 16 + u];
        at[u] = a > 0.0f ? a : 0.01f * a;
    }
    float mx = at[0];
#pragma unroll
    for (int u = 1; u < 16; ++u) mx = fmaxf(mx, at[u]);
    float e[16];
    float ssum = 0.0f;
#pragma unroll
    for (int u = 0; u < 16; ++u) { e[u] = __expf(at[u] - mx); ssum += e[u]; }
    float inv = 1.0f / ssum;
#pragma unroll
    for (int u = 0; u < 16; ++u) red[tid][u] = e[u] * inv * pg[u];
    __syncthreads();
    for (int s = 64; s > 0; s >>= 1) {
        if (tid < s) {
#pragma unroll
            for (int u = 0; u < 16; ++u) red[tid][u] += red[tid + s][u];
        }
        __syncthreads();
    }
    if (tid < 16) sh[tid] = ls[(size_t)link * 16 + tid];
    __syncthreads();
    if (tid < 16) {
        int d = tid;
        float az = gb[d], ar = gb[16 + d], ac = gb[32 + d];
        float gz = gb[48 + d], gr = gb[64 + d], gc = gb[80 + d];
#pragma unroll
        for (int i = 0; i < 16; ++i) {
            float mi = red[0][i];
            float hi = sh[i];
            az += mi * gk[i * 48 + d];
            ar += mi * gk[i * 48 + 16 + d];
            ac += mi * gk[i * 48 + 32 + d];
            gz += hi * grk[i * 48 + d];
            gr += hi * grk[i * 48 + 16 + d];
            gc += hi * grk[i * 48 + 32 + d];
        }
        float z = sigm(az + gz);
        float r = sigm(ar + gr);
        float c = tanhfast(ac + r * gc);
        float hn = z * sh[d] + (1.0f - z) * c;
        ls[(size_t)link * 16 + d] = hn;
        sh2[d] = hn;
    }
    __syncthreads();
    if (tid < 48) {
        float a = pgb[tid];
#pragma unroll
        for (int i = 0; i < 16; ++i) a += sh2[i] * pgk[i * 48 + tid];
        xk[(size_t)link * 48 + tid] = a;
    }
}

// ---------------- K4: KAN readout ----------------
// M 0: read f32 seq [f][9][16] rows 1..8; M 1: read f32 seqF [f][8][16]
template <int M>
__global__ __launch_bounds__(256, 1) void k_kan(
    const float* __restrict__ seqf, const int* __restrict__ ltp,
    const float* __restrict__ cap,
    const float* __restrict__ sp1, const float* __restrict__ ba1,
    const float* __restrict__ bi1,
    const float* __restrict__ sp2, const float* __restrict__ ba2,
    const float* __restrict__ bi2,
    float* __restrict__ out) {
    __shared__ float s1[2048], sba1[256], sbi1[16], s2[128], sba2[16];
    int tid = threadIdx.x;
#pragma unroll
    for (int i = tid; i < 2048; i += 256) s1[i] = sp1[i];
    sba1[tid] = ba1[tid];
    if (tid < 16) { sbi1[tid] = bi1[tid]; sba2[tid] = ba2[tid]; }
    if (tid < 128) s2[tid] = sp2[tid];
    __syncthreads();
    int gt = blockIdx.x * 256 + tid;
    int f = gt >> 3, t = gt & 7;
    float x[16];
    {
        const float4* xv = (M == 0)
            ? (const float4*)(seqf + ((size_t)f * 9 + 1 + t) * 16)
            : (const float4*)(seqf + ((size_t)f * 8 + t) * 16);
        float4* xr = (float4*)x;
        xr[0] = xv[0]; xr[1] = xv[1]; xr[2] = xv[2]; xr[3] = xv[3];
    }
    float hh[16];
#pragma unroll
    for (int u = 0; u < 16; ++u) hh[u] = sbi1[u];
#pragma unroll
    for (int i = 0; i < 16; ++i) {
        float B[8];
        bspline8(x[i], B);
#pragma unroll
        for (int b = 0; b < 8; ++b) {
            float Bb = B[b];
#pragma unroll
            for (int u = 0; u < 16; ++u) hh[u] += Bb * s1[(i * 8 + b) * 16 + u];
        }
        float sil = x[i] * sigm(x[i]);
#pragma unroll
        for (int u = 0; u < 16; ++u) hh[u] += sil * sba1[i * 16 + u];
    }
    float occ = bi2[0];
#pragma unroll
    for (int i = 0; i < 16; ++i) {
        float B[8];
        bspline8(hh[i], B);
#pragma unroll
        for (int b = 0; b < 8; ++b) occ += B[b] * s2[i * 8 + b];
        occ += hh[i] * sigm(hh[i]) * sba2[i];
    }
    int lk = ltp[(size_t)f * 8 + t];
    float val = occ / cap[lk];
#pragma unroll
    for (int off = 4; off; off >>= 1) val += __shfl_xor(val, off, 8);
    if (t == 0) out[f] = val;
}

extern "C" void kernel_launch(void* const* d_in, const int* in_sizes, int n_in,
                              void* d_out, int out_size, void* d_ws, size_t ws_size,
                              hipStream_t stream) {
    const float* f_tr   = (const float*)d_in[0];
    const float* f_pk   = (const float*)d_in[1];
    const float* f_ppb  = (const float*)d_in[2];
    const float* f_bpb  = (const float*)d_in[3];
    const float* f_psz  = (const float*)d_in[4];
    const float* f_p90  = (const float*)d_in[5];
    const float* f_rate = (const float*)d_in[6];
    const float* f_ipgm = (const float*)d_in[7];
    const float* f_ibg  = (const float*)d_in[8];
    const float* f_ipgv = (const float*)d_in[9];
    const float* f_type = (const float*)d_in[10];
    const float* f_cap  = (const float*)d_in[11];
    const float* f_mll  = (const float*)d_in[12];
    const int*   i_flen = (const int*)d_in[13];
    const int*   i_ltp  = (const int*)d_in[15];
    const int*   i_p2l  = (const int*)d_in[16];
    const float* fe_w1 = (const float*)d_in[17];
    const float* fe_b1 = (const float*)d_in[18];
    const float* fe_w2 = (const float*)d_in[19];
    const float* fe_b2 = (const float*)d_in[20];
    const float* le_w1 = (const float*)d_in[21];
    const float* le_b1 = (const float*)d_in[22];
    const float* le_w2 = (const float*)d_in[23];
    const float* le_b2 = (const float*)d_in[24];
    const float* at_w  = (const float*)d_in[25];
    const float* at_b  = (const float*)d_in[26];
    const float* pg_k  = (const float*)d_in[27];
    const float* pg_rk = (const float*)d_in[28];
    const float* pg_b  = (const float*)d_in[29];
    const float* lg_k  = (const float*)d_in[30];
    const float* lg_rk = (const float*)d_in[31];
    const float* lg_b  = (const float*)d_in[32];
    const float* k1_sp = (const float*)d_in[33];
    const float* k1_ba = (const float*)d_in[34];
    const float* k1_bi = (const float*)d_in[35];
    const float* k2_sp = (const float*)d_in[36];
    const float* k2_ba = (const float*)d_in[37];
    const float* k2_bi = (const float*)d_in[38];

    float* ws = (float*)d_ws;
    float* ps   = ws;
    float* ls   = ps + (size_t)NF * 16;
    float* xk   = ls + (size_t)NL * 16;
    float* load = xk + (size_t)NL * 48;
    float* tail = load + NL;
    size_t head_bytes = (size_t)(tail - ws) * 4;
    unsigned short* seqb = (unsigned short*)tail;          // bf16 [8][NF][16]
    size_t seqb_elems = (size_t)NF * 8 * 16;
    float* seqfL = (float*)(seqb + seqb_elems);            // f32 [NF][8][16]
    size_t need_bf = head_bytes + seqb_elems * 2 + (size_t)NF * 8 * 16 * 4;
    float* seq32 = tail;                                   // fallback f32 [NF][9][16]
    bool bfp = ws_size >= need_bf;
    float* out = (float*)d_out;

    k_load<<<NL * 64 / 256, 256, 0, stream>>>(i_p2l, f_tr, f_cap, load);
    k_flow_enc<<<NF / 256, 256, 0, stream>>>(f_tr, f_pk, f_ppb, f_bpb, f_psz, f_p90,
                                             f_rate, f_ipgm, f_ibg, f_ipgv, f_type,
                                             i_flen, fe_w1, fe_b1, fe_w2, fe_b2, ps);
    k_link_enc<<<NL / 256, 256, 0, stream>>>(f_cap, load, f_mll, le_w1, le_b1, le_w2,
                                             le_b2, ls, xk, pg_k, pg_b);
    if (bfp) {
        for (int it = 0; it < 12; ++it) {
            if (it < 11) {
                k_path4<1><<<NF * 4 / 256, 256, 0, stream>>>(xk, i_ltp, ps, seqb,
                                                             nullptr, pg_rk, pg_b);
                k_link_upd<true><<<NL, 128, 0, stream>>>(seqb, i_p2l, ls, at_w, at_b,
                                                         lg_k, lg_rk, lg_b, xk, pg_k, pg_b);
            } else {
                k_path4<2><<<NF * 4 / 256, 256, 0, stream>>>(xk, i_ltp, ps, nullptr,
                                                             seqfL, pg_rk, pg_b);
            }
        }
        k_kan<1><<<NF * 8 / 256, 256, 0, stream>>>(seqfL, i_ltp, f_cap, k1_sp, k1_ba,
                                                   k1_bi, k2_sp, k2_ba, k2_bi, out);
    } else {
        for (int it = 0; it < 12; ++it) {
            k_path4<0><<<NF * 4 / 256, 256, 0, stream>>>(xk, i_ltp, ps, nullptr,
                                                         seq32, pg_rk, pg_b);
            if (it < 11)
                k_link_upd<false><<<NL, 128, 0, stream>>>(seq32, i_p2l, ls, at_w, at_b,
                                                          lg_k, lg_rk, lg_b, xk, pg_k, pg_b);
        }
        k_kan<0><<<NF * 8 / 256, 256, 0, stream>>>(seq32, i_ltp, f_cap, k1_sp, k1_ba,
                                                   k1_bi, k2_sp, k2_ba, k2_bi, out);
    }
}

// Round 3
// 887.743 us; speedup vs baseline: 3.2981x; 3.2981x over previous
//
#include <hip/hip_runtime.h>
#include <cstdint>

#define NF 65536
#define PL 8
#define NL 4096
#define PPL 128
#define XKS 64  // padded xk record stride (floats): 256 B, cacheline-aligned

__device__ __forceinline__ float sigm(float v) { return 1.0f / (1.0f + __expf(-v)); }
__device__ __forceinline__ float tanhfast(float v) {
    float e = __expf(2.0f * v);
    return 1.0f - 2.0f / (e + 1.0f);
}
__device__ __forceinline__ float seluf(float x) {
    return x > 0.0f ? 1.0507009873554805f * x : 1.7580993408473766f * (__expf(x) - 1.0f);
}
__device__ __forceinline__ unsigned short f2bf(float x) {
    unsigned u = __float_as_uint(x);
    u += 0x7fffu + ((u >> 16) & 1u);
    return (unsigned short)(u >> 16);
}
__device__ __forceinline__ float bflo(unsigned u) { return __uint_as_float(u << 16); }
__device__ __forceinline__ float bfhi(unsigned u) { return __uint_as_float(u & 0xffff0000u); }

// Cubic B-spline basis, 8 bases, knots t_j = (j-3)*0.4 - 1 (matches jnp _knots)
__device__ __forceinline__ void bspline8(float xx, float* B) {
    float kn[12];
#pragma unroll
    for (int j = 0; j < 12; ++j) kn[j] = (float)(j - 3) * 0.4f - 1.0f;
    float b0[11];
#pragma unroll
    for (int j = 0; j < 11; ++j) b0[j] = (xx >= kn[j] && xx < kn[j + 1]) ? 1.0f : 0.0f;
    float b1[10];
#pragma unroll
    for (int j = 0; j < 10; ++j)
        b1[j] = (xx - kn[j]) * (1.0f / (kn[j + 1] - kn[j])) * b0[j] +
                (kn[j + 2] - xx) * (1.0f / (kn[j + 2] - kn[j + 1])) * b0[j + 1];
    float b2[9];
#pragma unroll
    for (int j = 0; j < 9; ++j)
        b2[j] = (xx - kn[j]) * (1.0f / (kn[j + 2] - kn[j])) * b1[j] +
                (kn[j + 3] - xx) * (1.0f / (kn[j + 3] - kn[j + 1])) * b1[j + 1];
#pragma unroll
    for (int j = 0; j < 8; ++j)
        B[j] = (xx - kn[j]) * (1.0f / (kn[j + 3] - kn[j])) * b2[j] +
               (kn[j + 4] - xx) * (1.0f / (kn[j + 4] - kn[j + 1])) * b2[j + 1];
}

// ---------------- S1: per-link load ----------------
__global__ __launch_bounds__(256) void k_load(const int* __restrict__ p2l,
                                              const float* __restrict__ ft,
                                              const float* __restrict__ cap,
                                              float* __restrict__ load) {
    int gid = blockIdx.x * 256 + threadIdx.x;
    int link = gid >> 6;
    int lane = threadIdx.x & 63;
    const int2* b2 = (const int2*)(p2l + (size_t)link * PPL * 2);
    int2 v0 = b2[lane];
    int2 v1 = b2[lane + 64];
    float s = ft[v0.x] + ft[v1.x];
#pragma unroll
    for (int off = 32; off; off >>= 1) s += __shfl_xor(s, off);
    if (lane == 0) load[link] = s / (cap[link] * 1e9f);
}

// ---------------- S2: flow encoder -> path_state ----------------
__global__ __launch_bounds__(256) void k_flow_enc(
    const float* __restrict__ tr, const float* __restrict__ pk,
    const float* __restrict__ ppb, const float* __restrict__ bpb,
    const float* __restrict__ psz, const float* __restrict__ p90,
    const float* __restrict__ rate, const float* __restrict__ ipgm,
    const float* __restrict__ ibg, const float* __restrict__ ipgv,
    const float* __restrict__ ftype, const int* __restrict__ flen,
    const float* __restrict__ w1, const float* __restrict__ b1,
    const float* __restrict__ w2, const float* __restrict__ b2,
    float* __restrict__ ps) {
    __shared__ float sw1[13 * 16], sb1[16], sw2[256], sb2[16];
    int tid = threadIdx.x;
    if (tid < 208) sw1[tid] = w1[tid];
    sw2[tid] = w2[tid];
    if (tid < 16) { sb1[tid] = b1[tid]; sb2[tid] = b2[tid]; }
    __syncthreads();
    int f = blockIdx.x * 256 + tid;
    float feat[13];
    feat[0] = (tr[f] - 0.5f) * 2.0f;
    feat[1] = (pk[f] - 0.5f) * 2.0f;
    feat[2] = (ibg[f] - 0.5f) * 2.0f;
    feat[3] = (rate[f] - 0.5f) * 2.0f;
    feat[4] = (p90[f] - 0.5f) * 2.0f;
    feat[5] = (psz[f] - 0.5f) * 2.0f;
    feat[6] = (bpb[f] - 0.5f) * 2.0f;
    feat[7] = (ipgm[f] - 0.5f) * 2.0f;
    feat[8] = (ipgv[f] - 0.5f) * 2.0f;
    feat[9] = (ppb[f] - 0.5f) * 2.0f;
    feat[10] = (float)flen[f];
    float2 ft2 = ((const float2*)ftype)[f];
    feat[11] = ft2.x;
    feat[12] = ft2.y;
    float t1[16];
#pragma unroll
    for (int u = 0; u < 16; ++u) {
        float a = sb1[u];
#pragma unroll
        for (int i = 0; i < 13; ++i) a += feat[i] * sw1[i * 16 + u];
        t1[u] = seluf(a);
    }
    float out[16];
#pragma unroll
    for (int u = 0; u < 16; ++u) {
        float a = sb2[u];
#pragma unroll
        for (int i = 0; i < 16; ++i) a += t1[i] * sw2[i * 16 + u];
        out[u] = seluf(a);
    }
    float4* o4 = (float4*)(ps + (size_t)f * 16);
    const float4* s4 = (const float4*)out;
#pragma unroll
    for (int q = 0; q < 4; ++q) o4[q] = s4[q];
}

// ---------------- S3: link encoder -> link_state (+ xk fold) ----------------
__global__ __launch_bounds__(256) void k_link_enc(
    const float* __restrict__ cap, const float* __restrict__ load,
    const float* __restrict__ mll,
    const float* __restrict__ w1, const float* __restrict__ b1,
    const float* __restrict__ w2, const float* __restrict__ b2,
    float* __restrict__ ls, float* __restrict__ xk,
    const float* __restrict__ pgk, const float* __restrict__ pgb) {
    int l = blockIdx.x * 256 + threadIdx.x;
    if (l >= NL) return;
    float f0 = (cap[l] - 5.0f) * 0.25f;
    float f1 = load[l];
    float f2 = f1 / mll[0];
    float f3 = 8.0f / 32768.0f;
    float t1[16];
#pragma unroll
    for (int u = 0; u < 16; ++u) {
        float a = b1[u] + f0 * w1[u] + f1 * w1[16 + u] + f2 * w1[32 + u] + f3 * w1[48 + u];
        t1[u] = seluf(a);
    }
    float out[16];
#pragma unroll
    for (int u = 0; u < 16; ++u) {
        float a = b2[u];
#pragma unroll
        for (int i = 0; i < 16; ++i) a += t1[i] * w2[i * 16 + u];
        out[u] = seluf(a);
    }
    float4* o4 = (float4*)(ls + (size_t)l * 16);
    const float4* s4 = (const float4*)out;
#pragma unroll
    for (int q = 0; q < 4; ++q) o4[q] = s4[q];
    for (int u = 0; u < 48; ++u) {
        float a = pgb[u];
#pragma unroll
        for (int i = 0; i < 16; ++i) a += out[i] * pgk[i * 48 + u];
        xk[(size_t)l * XKS + u] = a;
    }
}

// ---------------- K1: path GRU, 4 threads per flow (no local arrays!) ----------------
// MODE 0: f32 seq [f][9][16] rows 0..8; MODE 1: bf16 seq [t][NF][16] rows 0..7;
// MODE 2: f32 seqF [f][8][16] rows 1..8 (KAN input)
template <int MODE>
__global__ __launch_bounds__(256) void k_path4(
    const float* __restrict__ xk, const int* __restrict__ ltp,
    float* __restrict__ ps, unsigned short* __restrict__ seqb,
    float* __restrict__ seqf,
    const float* __restrict__ grk, const float* __restrict__ gb) {
    __shared__ float srk[768], sbg[48];
    int tid = threadIdx.x;
    for (int i = tid; i < 768; i += 256) srk[i] = grk[i];
    if (tid < 48) sbg[tid] = gb[48 + tid];
    __syncthreads();
    int gid = blockIdx.x * 256 + tid;
    int f = gid >> 2, sub = gid & 3;
    float4 h = *(const float4*)(ps + (size_t)f * 16 + sub * 4);
    if (MODE == 0) {
        *(float4*)(seqf + (size_t)f * 9 * 16 + sub * 4) = h;
    } else if (MODE == 1) {
        ushort4 u4;
        u4.x = f2bf(h.x); u4.y = f2bf(h.y); u4.z = f2bf(h.z); u4.w = f2bf(h.w);
        *(ushort4*)(seqb + (size_t)f * 16 + sub * 4) = u4;  // row 0
    }
    float4 bz = *(const float4*)(sbg + sub * 4);
    float4 br = *(const float4*)(sbg + 16 + sub * 4);
    float4 bc = *(const float4*)(sbg + 32 + sub * 4);
    for (int t = 0; t < 8; ++t) {
        int lk = ltp[(size_t)f * 8 + t];
        const float* xb = xk + (size_t)lk * XKS + sub * 4;
        float4 za = *(const float4*)xb;         // x-side z gate, accumulates h-side too
        float4 ra = *(const float4*)(xb + 16);  // x-side r gate
        float4 ca = *(const float4*)(xb + 32);  // x-side c gate (kept separate)
        za.x += bz.x; za.y += bz.y; za.z += bz.z; za.w += bz.w;
        ra.x += br.x; ra.y += br.y; ra.z += br.z; ra.w += br.w;
        float4 cg = bc;                         // h-side c gate accumulator
#pragma unroll
        for (int i = 0; i < 16; ++i) {
            float hsrc = ((i & 3) == 0) ? h.x : ((i & 3) == 1) ? h.y
                       : ((i & 3) == 2) ? h.z : h.w;
            float hi = __shfl(hsrc, i >> 2, 4);
            const float* w = srk + i * 48 + sub * 4;
            float4 wz = *(const float4*)w;
            float4 wr = *(const float4*)(w + 16);
            float4 wc = *(const float4*)(w + 32);
            za.x += hi * wz.x; za.y += hi * wz.y; za.z += hi * wz.z; za.w += hi * wz.w;
            ra.x += hi * wr.x; ra.y += hi * wr.y; ra.z += hi * wr.z; ra.w += hi * wr.w;
            cg.x += hi * wc.x; cg.y += hi * wc.y; cg.z += hi * wc.z; cg.w += hi * wc.w;
        }
        {
            float z = sigm(za.x), r = sigm(ra.x);
            float c = tanhfast(ca.x + r * cg.x);
            h.x = z * h.x + (1.0f - z) * c;
            z = sigm(za.y); r = sigm(ra.y);
            c = tanhfast(ca.y + r * cg.y);
            h.y = z * h.y + (1.0f - z) * c;
            z = sigm(za.z); r = sigm(ra.z);
            c = tanhfast(ca.z + r * cg.z);
            h.z = z * h.z + (1.0f - z) * c;
            z = sigm(za.w); r = sigm(ra.w);
            c = tanhfast(ca.w + r * cg.w);
            h.w = z * h.w + (1.0f - z) * c;
        }
        if (MODE == 0) {
            *(float4*)(seqf + ((size_t)f * 9 + t + 1) * 16 + sub * 4) = h;
        } else if (MODE == 1) {
            if (t < 7) {  // row 8 never gathered (p_pos < 8)
                ushort4 u4;
                u4.x = f2bf(h.x); u4.y = f2bf(h.y); u4.z = f2bf(h.z); u4.w = f2bf(h.w);
                *(ushort4*)(seqb + ((size_t)(t + 1) * NF + f) * 16 + sub * 4) = u4;
            }
        } else {
            *(float4*)(seqf + ((size_t)f * 8 + t) * 16 + sub * 4) = h;
        }
    }
    if (MODE != 2) *(float4*)(ps + (size_t)f * 16 + sub * 4) = h;
}

// ---------------- K2: attention message + link GRU (+ xk fold) ----------------
template <bool BF16>
__global__ __launch_bounds__(128) void k_link_upd(
    const void* __restrict__ seqv, const int* __restrict__ p2l,
    float* __restrict__ ls,
    const float* __restrict__ aw, const float* __restrict__ ab,
    const float* __restrict__ gk, const float* __restrict__ grk,
    const float* __restrict__ gb,
    float* __restrict__ xk, const float* __restrict__ pgk,
    const float* __restrict__ pgb) {
    __shared__ float sW[256], sB[16], red[128][17], sh[16], sh2[16];
    int tid = threadIdx.x;
    int link = blockIdx.x;
    sW[tid] = aw[tid];
    sW[tid + 128] = aw[tid + 128];
    if (tid < 16) sB[tid] = ab[tid];
    __syncthreads();
    int2 pp = ((const int2*)p2l)[(size_t)link * PPL + tid];
    float pg[16];
    if (BF16) {
        const unsigned short* sp =
            (const unsigned short*)seqv + ((size_t)pp.y * NF + pp.x) * 16;
        uint4 q0 = *(const uint4*)sp;
        uint4 q1 = *(const uint4*)(sp + 8);
        pg[0] = bflo(q0.x); pg[1] = bfhi(q0.x); pg[2] = bflo(q0.y); pg[3] = bfhi(q0.y);
        pg[4] = bflo(q0.z); pg[5] = bfhi(q0.z); pg[6] = bflo(q0.w); pg[7] = bfhi(q0.w);
        pg[8] = bflo(q1.x); pg[9] = bfhi(q1.x); pg[10] = bflo(q1.y); pg[11] = bfhi(q1.y);
        pg[12] = bflo(q1.z); pg[13] = bfhi(q1.z); pg[14] = bflo(q1.w); pg[15] = bfhi(q1.w);
    } else {
        const float4* pv =
            (const float4*)((const float*)seqv + ((size_t)pp.x * 9 + pp.y) * 16);
        float4* pr = (float4*)pg;
        pr[0] = pv[0]; pr[1] = pv[1]; pr[2] = pv[2]; pr[3] = pv[3];
    }
    float at[16];
#pragma unroll
    for (int u = 0; u < 16; ++u) {
        float a = sB[u];
#pragma unroll
        for (int i = 0; i < 16; ++i) a += pg[i] * sW[i * 16 + u];
        at[u] = a > 0.0f ? a : 0.01f * a;
    }
    float mx = at[0];
#pragma unroll
    for (int u = 1; u < 16; ++u) mx = fmaxf(mx, at[u]);
    float e[16];
    float ssum = 0.0f;
#pragma unroll
    for (int u = 0; u < 16; ++u) { e[u] = __expf(at[u] - mx); ssum += e[u]; }
    float inv = 1.0f / ssum;
#pragma unroll
    for (int u = 0; u < 16; ++u) red[tid][u] = e[u] * inv * pg[u];
    __syncthreads();
    for (int s = 64; s > 0; s >>= 1) {
        if (tid < s) {
#pragma unroll
            for (int u = 0; u < 16; ++u) red[tid][u] += red[tid + s][u];
        }
        __syncthreads();
    }
    if (tid < 16) sh[tid] = ls[(size_t)link * 16 + tid];
    __syncthreads();
    if (tid < 16) {
        int d = tid;
        float az = gb[d], ar = gb[16 + d], ac = gb[32 + d];
        float gz = gb[48 + d], gr = gb[64 + d], gc = gb[80 + d];
#pragma unroll
        for (int i = 0; i < 16; ++i) {
            float mi = red[0][i];
            float hi = sh[i];
            az += mi * gk[i * 48 + d];
            ar += mi * gk[i * 48 + 16 + d];
            ac += mi * gk[i * 48 + 32 + d];
            gz += hi * grk[i * 48 + d];
            gr += hi * grk[i * 48 + 16 + d];
            gc += hi * grk[i * 48 + 32 + d];
        }
        float z = sigm(az + gz);
        float r = sigm(ar + gr);
        float c = tanhfast(ac + r * gc);
        float hn = z * sh[d] + (1.0f - z) * c;
        ls[(size_t)link * 16 + d] = hn;
        sh2[d] = hn;
    }
    __syncthreads();
    if (tid < 48) {
        float a = pgb[tid];
#pragma unroll
        for (int i = 0; i < 16; ++i) a += sh2[i] * pgk[i * 48 + tid];
        xk[(size_t)link * XKS + tid] = a;
    }
}

// ---------------- K4: KAN readout ----------------
template <int M>
__global__ __launch_bounds__(256, 1) void k_kan(
    const float* __restrict__ seqf, const int* __restrict__ ltp,
    const float* __restrict__ cap,
    const float* __restrict__ sp1, const float* __restrict__ ba1,
    const float* __restrict__ bi1,
    const float* __restrict__ sp2, const float* __restrict__ ba2,
    const float* __restrict__ bi2,
    float* __restrict__ out) {
    __shared__ float s1[2048], sba1[256], sbi1[16], s2[128], sba2[16];
    int tid = threadIdx.x;
#pragma unroll
    for (int i = tid; i < 2048; i += 256) s1[i] = sp1[i];
    sba1[tid] = ba1[tid];
    if (tid < 16) { sbi1[tid] = bi1[tid]; sba2[tid] = ba2[tid]; }
    if (tid < 128) s2[tid] = sp2[tid];
    __syncthreads();
    int gt = blockIdx.x * 256 + tid;
    int f = gt >> 3, t = gt & 7;
    float x[16];
    {
        const float4* xv = (M == 0)
            ? (const float4*)(seqf + ((size_t)f * 9 + 1 + t) * 16)
            : (const float4*)(seqf + ((size_t)f * 8 + t) * 16);
        float4* xr = (float4*)x;
        xr[0] = xv[0]; xr[1] = xv[1]; xr[2] = xv[2]; xr[3] = xv[3];
    }
    float hh[16];
#pragma unroll
    for (int u = 0; u < 16; ++u) hh[u] = sbi1[u];
#pragma unroll
    for (int i = 0; i < 16; ++i) {
        float B[8];
        bspline8(x[i], B);
#pragma unroll
        for (int b = 0; b < 8; ++b) {
            float Bb = B[b];
#pragma unroll
            for (int u = 0; u < 16; ++u) hh[u] += Bb * s1[(i * 8 + b) * 16 + u];
        }
        float sil = x[i] * sigm(x[i]);
#pragma unroll
        for (int u = 0; u < 16; ++u) hh[u] += sil * sba1[i * 16 + u];
    }
    float occ = bi2[0];
#pragma unroll
    for (int i = 0; i < 16; ++i) {
        float B[8];
        bspline8(hh[i], B);
#pragma unroll
        for (int b = 0; b < 8; ++b) occ += B[b] * s2[i * 8 + b];
        occ += hh[i] * sigm(hh[i]) * sba2[i];
    }
    int lk = ltp[(size_t)f * 8 + t];
    float val = occ / cap[lk];
#pragma unroll
    for (int off = 4; off; off >>= 1) val += __shfl_xor(val, off, 8);
    if (t == 0) out[f] = val;
}

extern "C" void kernel_launch(void* const* d_in, const int* in_sizes, int n_in,
                              void* d_out, int out_size, void* d_ws, size_t ws_size,
                              hipStream_t stream) {
    const float* f_tr   = (const float*)d_in[0];
    const float* f_pk   = (const float*)d_in[1];
    const float* f_ppb  = (const float*)d_in[2];
    const float* f_bpb  = (const float*)d_in[3];
    const float* f_psz  = (const float*)d_in[4];
    const float* f_p90  = (const float*)d_in[5];
    const float* f_rate = (const float*)d_in[6];
    const float* f_ipgm = (const float*)d_in[7];
    const float* f_ibg  = (const float*)d_in[8];
    const float* f_ipgv = (const float*)d_in[9];
    const float* f_type = (const float*)d_in[10];
    const float* f_cap  = (const float*)d_in[11];
    const float* f_mll  = (const float*)d_in[12];
    const int*   i_flen = (const int*)d_in[13];
    const int*   i_ltp  = (const int*)d_in[15];
    const int*   i_p2l  = (const int*)d_in[16];
    const float* fe_w1 = (const float*)d_in[17];
    const float* fe_b1 = (const float*)d_in[18];
    const float* fe_w2 = (const float*)d_in[19];
    const float* fe_b2 = (const float*)d_in[20];
    const float* le_w1 = (const float*)d_in[21];
    const float* le_b1 = (const float*)d_in[22];
    const float* le_w2 = (const float*)d_in[23];
    const float* le_b2 = (const float*)d_in[24];
    const float* at_w  = (const float*)d_in[25];
    const float* at_b  = (const float*)d_in[26];
    const float* pg_k  = (const float*)d_in[27];
    const float* pg_rk = (const float*)d_in[28];
    const float* pg_b  = (const float*)d_in[29];
    const float* lg_k  = (const float*)d_in[30];
    const float* lg_rk = (const float*)d_in[31];
    const float* lg_b  = (const float*)d_in[32];
    const float* k1_sp = (const float*)d_in[33];
    const float* k1_ba = (const float*)d_in[34];
    const float* k1_bi = (const float*)d_in[35];
    const float* k2_sp = (const float*)d_in[36];
    const float* k2_ba = (const float*)d_in[37];
    const float* k2_bi = (const float*)d_in[38];

    float* ws = (float*)d_ws;
    float* ps   = ws;
    float* ls   = ps + (size_t)NF * 16;
    float* xk   = ls + (size_t)NL * 16;
    float* load = xk + (size_t)NL * XKS;
    float* tail = load + NL;
    size_t head_bytes = (size_t)(tail - ws) * 4;
    unsigned short* seqb = (unsigned short*)tail;          // bf16 [8][NF][16]
    size_t seqb_elems = (size_t)NF * 8 * 16;
    float* seqfL = (float*)(seqb + seqb_elems);            // f32 [NF][8][16]
    size_t need_bf = head_bytes + seqb_elems * 2 + (size_t)NF * 8 * 16 * 4;
    float* seq32 = tail;                                   // fallback f32 [NF][9][16]
    bool bfp = ws_size >= need_bf;
    float* out = (float*)d_out;

    k_load<<<NL * 64 / 256, 256, 0, stream>>>(i_p2l, f_tr, f_cap, load);
    k_flow_enc<<<NF / 256, 256, 0, stream>>>(f_tr, f_pk, f_ppb, f_bpb, f_psz, f_p90,
                                             f_rate, f_ipgm, f_ibg, f_ipgv, f_type,
                                             i_flen, fe_w1, fe_b1, fe_w2, fe_b2, ps);
    k_link_enc<<<NL / 256, 256, 0, stream>>>(f_cap, load, f_mll, le_w1, le_b1, le_w2,
                                             le_b2, ls, xk, pg_k, pg_b);
    if (bfp) {
        for (int it = 0; it < 12; ++it) {
            if (it < 11) {
                k_path4<1><<<NF * 4 / 256, 256, 0, stream>>>(xk, i_ltp, ps, seqb,
                                                             nullptr, pg_rk, pg_b);
                k_link_upd<true><<<NL, 128, 0, stream>>>(seqb, i_p2l, ls, at_w, at_b,
                                                         lg_k, lg_rk, lg_b, xk, pg_k, pg_b);
            } else {
                k_path4<2><<<NF * 4 / 256, 256, 0, stream>>>(xk, i_ltp, ps, nullptr,
                                                             seqfL, pg_rk, pg_b);
            }
        }
        k_kan<1><<<NF * 8 / 256, 256, 0, stream>>>(seqfL, i_ltp, f_cap, k1_sp, k1_ba,
                                                   k1_bi, k2_sp, k2_ba, k2_bi, out);
    } else {
        for (int it = 0; it < 12; ++it) {
            k_path4<0><<<NF * 4 / 256, 256, 0, stream>>>(xk, i_ltp, ps, nullptr,
                                                         seq32, pg_rk, pg_b);
            if (it < 11)
                k_link_upd<false><<<NL, 128, 0, stream>>>(seq32, i_p2l, ls, at_w, at_b,
                                                          lg_k, lg_rk, lg_b, xk, pg_k, pg_b);
        }
        k_kan<0><<<NF * 8 / 256, 256, 0, stream>>>(seq32, i_ltp, f_cap, k1_sp, k1_ba,
                                                   k1_bi, k2_sp, k2_ba, k2_bi, out);
    }
}